// Round 11
// baseline (138.262 us; speedup 1.0000x reference)
//
#include <hip/hip_runtime.h>
#include <stdint.h>

#define NB    64      // batch
#define NROI  6000    // proposals per image
#define KGT   100     // gt slots per image
#define NT    6100    // NROI + KGT
#define ROUT  256     // sampled rois per image
#define FGPER 64

#define BLOCKA 256                      // iou block
#define ROIS_PER_BLOCK (BLOCKA * 2)     // 2 rois per thread
#define NCHA ((NT + ROIS_PER_BLOCK - 1) / ROIS_PER_BLOCK)   // 12
#define CHUNK 8                         // GTs staged into registers per chunk

#define BLOCK 512
#define NWAVE (BLOCK / 64)
#define SEG 96                 // ceil(6100/64) = 96 segments of 64
#define SEGW (SEG / NWAVE)     // 12 segments per wave
#define CANDMAX 128

// class encoding in ws u16: (cls << 8) | gt_assign ; cls: 2=fg, 1=bg, 0=neg(-1 row)
#define CLS_FG 2
#define CLS_BG 1
#define CLS_NEG 0

__device__ __forceinline__ uint32_t rotl32(uint32_t v, int s) { return (v << s) | (v >> (32 - s)); }

// Exact replica of JAX threefry2x32 (20 rounds)
#define TFR(r) { x0 += x1; x1 = rotl32(x1, r); x1 ^= x0; }
__device__ __forceinline__ void tf2x32(uint32_t k0, uint32_t k1, uint32_t& x0, uint32_t& x1) {
  uint32_t k2 = k0 ^ k1 ^ 0x1BD11BDAu;
  x0 += k0; x1 += k1;
  TFR(13) TFR(15) TFR(26) TFR(6)
  x0 += k1; x1 += k2 + 1u;
  TFR(17) TFR(29) TFR(16) TFR(24)
  x0 += k2; x1 += k0 + 2u;
  TFR(13) TFR(15) TFR(26) TFR(6)
  x0 += k0; x1 += k1 + 3u;
  TFR(17) TFR(29) TFR(16) TFR(24)
  x0 += k1; x1 += k2 + 4u;
  TFR(13) TFR(15) TFR(26) TFR(6)
  x0 += k2; x1 += k0 + 5u;
}

// jax_threefry_partitionable=True (default since JAX 0.4.36):
// bits for flat index i = fold(TF(key, (0, i))) = out0 ^ out1
__device__ __forceinline__ uint32_t tf_bits32(uint32_t k0, uint32_t k1, uint32_t idx) {
  uint32_t x0 = 0u, x1 = idx;
  tf2x32(k0, k1, x0, x1);
  return x0 ^ x1;
}

// JAX uniform [0,1): bitcast(bits>>9 | 0x3F800000) - 1.0
__device__ __forceinline__ float u01f(uint32_t bits) {
  return __uint_as_float((bits >> 9) | 0x3F800000u) - 1.0f;
}

// Correctly-rounded f32 divide (canonical div_scale/rcp/NR/div_fmas/div_fixup).
// Bit-identical to IEEE fdiv on this kernel's operand domain (no denormals).
__device__ __forceinline__ float crdiv(float num, float den) {
  bool f0, f1;
  float ds = __builtin_amdgcn_div_scalef(num, den, false, &f0);
  float ns = __builtin_amdgcn_div_scalef(num, den, true,  &f1);
  float r  = __builtin_amdgcn_rcpf(ds);
  float e0 = __builtin_fmaf(-ds, r, 1.0f);
  float r1 = __builtin_fmaf(e0, r, r);
  float m  = ns * r1;
  float e1 = __builtin_fmaf(-ds, m, ns);
  float r2 = __builtin_fmaf(e1, r1, m);
  float e2 = __builtin_fmaf(-ds, r2, ns);
  float fm = __builtin_amdgcn_div_fmasf(e2, r1, r2, f1);
  return __builtin_amdgcn_div_fixupf(fm, den, num);
}

// ============================ kernel A: IoU max/argmax ============================
// grid (NCHA, NB) x BLOCKA, 2 rois/thread. Launched TWICE this round (idempotent)
// as a timing probe: dur_us delta vs R10 == one iou_kernel instance + dispatch overhead.
__global__ __launch_bounds__(BLOCKA) void iou_kernel(
    const float* __restrict__ all_rois,   // [NB, NROI, 5]
    const float* __restrict__ gt_boxes,   // [NB, KGT, 5]
    unsigned short* __restrict__ cls_ws)  // [NB, NT]
{
#pragma clang fp contract(off)
  __shared__ float s_gx1[KGT], s_gy1[KGT], s_gx2[KGT], s_gy2[KGT];   // original order (appended rois)
  __shared__ float4 s_cg[KGT + CHUNK];    // compacted valid (x1,y1,x2,y2)
  __shared__ float s_car[KGT + CHUNK];    // compacted area
  __shared__ short s_ck[KGT];             // compacted -> original k
  __shared__ unsigned long long s_zm[2];
  __shared__ int s_V, s_minz;

  const int b = blockIdx.y;
  const int tid = threadIdx.x;
  const int lane = tid & 63, wv = tid >> 6;

  bool nz = false;
  float gx1v = 0, gy1v = 0, gx2v = 0, gy2v = 0, garv = 0;
  if (tid < KGT) {
    const float* g = gt_boxes + ((size_t)b * KGT + tid) * 5;
    gx1v = g[0]; gy1v = g[1]; gx2v = g[2]; gy2v = g[3];
    s_gx1[tid] = gx1v; s_gy1[tid] = gy1v; s_gx2[tid] = gx2v; s_gy2[tid] = gy2v;
    float wg = __fadd_rn(__fadd_rn(gx2v, -gx1v), 1.0f);
    float hg = __fadd_rn(__fadd_rn(gy2v, -gy1v), 1.0f);
    garv = __fmul_rn(wg, hg);
    nz = !(wg == 1.0f && hg == 1.0f);
  }
  if (wv < 2) {
    unsigned long long bm = __ballot(nz);
    if (lane == 0) s_zm[wv] = bm;
  }
  __syncthreads();
  if (tid == 0) {
    unsigned long long z0 = s_zm[0], z1 = s_zm[1];
    unsigned long long g0 = ~z0;                                   // zero-rows among k=0..63
    unsigned long long g1 = (~z1) & ((1ull << (KGT - 64)) - 1ull); // k=64..99
    int mz = -1;
    if (g0) mz = __ffsll((long long)g0) - 1;
    else if (g1) mz = 64 + __ffsll((long long)g1) - 1;
    s_minz = mz;
    s_V = __popcll(z0) + __popcll(z1);
  }
  if (tid < KGT && nz) {
    unsigned long long lm = (1ull << lane) - 1ull;
    int pos = (wv == 0) ? __popcll(s_zm[0] & lm)
                        : __popcll(s_zm[0]) + __popcll(s_zm[1] & lm);
    s_cg[pos] = make_float4(gx1v, gy1v, gx2v, gy2v);
    s_car[pos] = garv; s_ck[pos] = (short)tid;
  }
  __syncthreads();
  const int V = s_V, minz = s_minz;

  // benign pad so tail-chunk register loads read defined values (updates are
  // predicated on vv < V, so pad can never win the argmax)
  if (tid < CHUNK) { s_cg[V + tid] = make_float4(0.f, 0.f, 0.f, 0.f); s_car[V + tid] = 1.0f; }
  __syncthreads();

  const int base = blockIdx.x * ROIS_PER_BLOCK;
  const int t0 = base + tid, t1 = base + BLOCKA + tid;

  // load two rois (guarded)
  float x1a, y1a, x2a, y2a, x1b, y1b, x2b, y2b;
  {
    int ta = (t0 < NT) ? t0 : 0;
    if (ta < NROI) {
      const float* p = all_rois + ((size_t)b * NROI + ta) * 5;
      x1a = p[1]; y1a = p[2]; x2a = p[3]; y2a = p[4];
    } else {
      int k = ta - NROI;
      x1a = s_gx1[k]; y1a = s_gy1[k]; x2a = s_gx2[k]; y2a = s_gy2[k];
    }
    int tb = (t1 < NT) ? t1 : 0;
    if (tb < NROI) {
      const float* p = all_rois + ((size_t)b * NROI + tb) * 5;
      x1b = p[1]; y1b = p[2]; x2b = p[3]; y2b = p[4];
    } else {
      int k = tb - NROI;
      x1b = s_gx1[k]; y1b = s_gy1[k]; x2b = s_gx2[k]; y2b = s_gy2[k];
    }
  }
  float wra = __fadd_rn(__fadd_rn(x2a, -x1a), 1.0f);
  float hra = __fadd_rn(__fadd_rn(y2a, -y1a), 1.0f);
  float ara = __fmul_rn(wra, hra);
  bool rza = (wra == 1.0f && hra == 1.0f);
  float wrb = __fadd_rn(__fadd_rn(x2b, -x1b), 1.0f);
  float hrb = __fadd_rn(__fadd_rn(y2b, -y1b), 1.0f);
  float arb = __fmul_rn(wrb, hrb);
  bool rzb = (wrb == 1.0f && hrb == 1.0f);

  float besta = -2.0f, bestb = -2.0f;
  int bva = -1, bvb = -1;            // compacted index of current argmax

  for (int c0 = 0; c0 < V; c0 += CHUNK) {
    float4 g[CHUNK];
    float ca[CHUNK];
#pragma unroll
    for (int i = 0; i < CHUNK; ++i) { g[i] = s_cg[c0 + i]; ca[i] = s_car[c0 + i]; }
#pragma unroll
    for (int i = 0; i < CHUNK; ++i) {
      const int vv = c0 + i;
      const float cx1 = g[i].x, cy1 = g[i].y, cx2 = g[i].z, cy2 = g[i].w, car = ca[i];
      {
        float iw = fmaxf(__fadd_rn(__fadd_rn(fminf(x2a, cx2), -fmaxf(x1a, cx1)), 1.0f), 0.0f);
        float ih = fmaxf(__fadd_rn(__fadd_rn(fminf(y2a, cy2), -fmaxf(y1a, cy1)), 1.0f), 0.0f);
        float inter = __fmul_rn(iw, ih);
        float ov = crdiv(inter, __fadd_rn(__fadd_rn(ara, car), -inter));
        if (vv < V && ov > besta) { besta = ov; bva = vv; }
      }
      {
        float iw = fmaxf(__fadd_rn(__fadd_rn(fminf(x2b, cx2), -fmaxf(x1b, cx1)), 1.0f), 0.0f);
        float ih = fmaxf(__fadd_rn(__fadd_rn(fminf(y2b, cy2), -fmaxf(y1b, cy1)), 1.0f), 0.0f);
        float inter = __fmul_rn(iw, ih);
        float ov = crdiv(inter, __fadd_rn(__fadd_rn(arb, car), -inter));
        if (vv < V && ov > bestb) { bestb = ov; bvb = vv; }
      }
    }
  }

  int bka = (bva >= 0) ? (int)s_ck[bva] : 0;
  int bkb = (bvb >= 0) ? (int)s_ck[bvb] : 0;
  // zero-gt fold (value exactly 0.0 at orig indices >= minz) + roi_zero override
  if (rza) { besta = -1.0f; bka = 0; }
  else {
    if (besta < 0.0f) { besta = 0.0f; bka = (minz >= 0 ? minz : 0); }
    else if (besta == 0.0f && minz >= 0 && minz < bka) bka = minz;
  }
  if (rzb) { bestb = -1.0f; bkb = 0; }
  else {
    if (bestb < 0.0f) { bestb = 0.0f; bkb = (minz >= 0 ? minz : 0); }
    else if (bestb == 0.0f && minz >= 0 && minz < bkb) bkb = minz;
  }
  int clsa = (besta >= 0.5f) ? CLS_FG : ((besta >= 0.0f) ? CLS_BG : CLS_NEG);
  int clsb = (bestb >= 0.5f) ? CLS_FG : ((bestb >= 0.0f) ? CLS_BG : CLS_NEG);
  if (t0 < NT) cls_ws[(size_t)b * NT + t0] = (unsigned short)((clsa << 8) | bka);
  if (t1 < NT) cls_ws[(size_t)b * NT + t1] = (unsigned short)((clsb << 8) | bkb);
}

// p-th (0-based) index t whose mask is FALSE, ascending (argsort 2.0-pad region). Never hot.
// mode 0: member = fg; mode 1: member = bg.
__device__ int nth_non(const unsigned short* cp, int n, int mode) {
  int c = 0;
  for (int t = 0; t < NT; ++t) {
    int cls = cp[t] >> 8;
    bool member = (mode == 0) ? (cls == CLS_FG) : (cls == CLS_BG);
    if (!member) { if (c == n) return t; ++c; }
  }
  return NT - 1;
}

// ====================== kernel B: compaction + select + sampling ======================
__global__ __launch_bounds__(BLOCK) void sample_kernel(
    const float* __restrict__ all_rois,
    const float* __restrict__ gt_boxes,
    const unsigned short* __restrict__ cls_ws,
    const float* __restrict__ bmeans,
    const float* __restrict__ bstds,
    const float* __restrict__ binw,
    float* __restrict__ out)
{
#pragma clang fp contract(off)
  __shared__ float s_gx1[KGT], s_gy1[KGT], s_gx2[KGT], s_gy2[KGT], s_glb[KGT];
  __shared__ uint64_t s_key[NT];            // fg keys, index-ordered
  __shared__ unsigned short s_bidx[NT];     // bg indices, ascending
  __shared__ unsigned short s_ford[NT];     // rank -> roi index (only r<64 used on hot path)
  __shared__ int s_cf[SEG], s_cb[SEG];
  __shared__ int s_pf[SEG + 1], s_pb[SEG + 1];
  __shared__ int s_hist[512];
  __shared__ int s_wtot[NWAVE];
  __shared__ uint64_t s_cand[CANDMAX];
  __shared__ int s_crank[CANDMAX];
  __shared__ int s_candN;

  const int b = blockIdx.x;
  const int tid = threadIdx.x;
  const int lane = tid & 63, wv = tid >> 6;
  const unsigned short* cp = cls_ws + (size_t)b * NT;

  if (tid < KGT) {
    const float* g = gt_boxes + ((size_t)b * KGT + tid) * 5;
    s_gx1[tid] = g[0]; s_gy1[tid] = g[1]; s_gx2[tid] = g[2]; s_gy2[tid] = g[3]; s_glb[tid] = g[4];
  }
  s_hist[tid] = 0;                      // BLOCK == 512 exactly
  if (tid < CANDMAX) s_crank[tid] = 0;
  if (tid == 0) s_candN = 0;

  // per-image keys (partitionable threefry):
  // keys[b] = TF((0,42),(0,b)); kf,kb,kr = TF(keys[b],(0,{0,1,2}))
  uint32_t kk0 = 0u, kk1 = (uint32_t)b;
  tf2x32(0u, 42u, kk0, kk1);
  uint32_t kf0 = 0u, kf1 = 0u; tf2x32(kk0, kk1, kf0, kf1);
  uint32_t kb0 = 0u, kb1 = 1u; tf2x32(kk0, kk1, kb0, kb1);
  uint32_t kr0 = 0u, kr1 = 2u; tf2x32(kk0, kk1, kr0, kr1);

  // ---- pass 1: per-segment fg/bg counts (no barriers inside) ----
  int fgbits = 0, bgbits = 0;
#pragma unroll
  for (int i = 0; i < SEGW; ++i) {
    int s = i * NWAVE + wv;
    int t = s * 64 + lane;
    int cls = (t < NT) ? (cp[t] >> 8) : -1;
    bool fg = (cls == CLS_FG);
    bool bg = (cls == CLS_BG);
    unsigned long long bf = __ballot(fg), bb = __ballot(bg);
    if (lane == 0) { s_cf[s] = __popcll(bf); s_cb[s] = __popcll(bb); }
    fgbits |= fg ? (1 << i) : 0;
    bgbits |= bg ? (1 << i) : 0;
  }
  __syncthreads();

  // ---- pass 2: exclusive scan of segment counts (wave 0: fg, wave 1: bg) ----
  if (wv < 2) {
    int* src = (wv == 0) ? s_cf : s_cb;
    int* dst = (wv == 0) ? s_pf : s_pb;
    int v0 = src[lane];
    int v1 = (lane < SEG - 64) ? src[64 + lane] : 0;
    int x = v0;
    for (int off = 1; off < 64; off <<= 1) { int n = __shfl_up(x, off); if (lane >= off) x += n; }
    int tot0 = __shfl(x, 63);
    int y = v1;
    for (int off = 1; off < 32; off <<= 1) { int n = __shfl_up(y, off); if (lane >= off) y += n; }
    int tot96 = tot0 + __shfl(y, 31);
    dst[lane] = x - v0;
    if (lane < SEG - 64) dst[64 + lane] = tot0 + (y - v1);
    if (lane == 0) dst[SEG] = tot96;
  }
  __syncthreads();
  const int F = s_pf[SEG], Bc = s_pb[SEG];

  // ---- pass 3: positioned writes (fg keys with threefry bits; bg indices) ----
#pragma unroll
  for (int i = 0; i < SEGW; ++i) {
    int s = i * NWAVE + wv;
    int t = s * 64 + lane;
    bool fg = (fgbits >> i) & 1, bg = (bgbits >> i) & 1;
    unsigned long long bf = __ballot(fg), bb = __ballot(bg);
    unsigned long long lm = (1ull << lane) - 1ull;
    if (fg) {
      uint32_t ub = tf_bits32(kf0, kf1, (uint32_t)t);   // uniform(kf,(NT,)) bits[t]
      s_key[s_pf[s] + __popcll(bf & lm)] = (((uint64_t)(ub >> 9)) << 32) | (uint32_t)t;
    }
    if (bg) s_bidx[s_pb[s] + __popcll(bb & lm)] = (unsigned short)t;
  }
  __syncthreads();

  // ---- rank-select: only ranks < 64 are read when Bc>0 (always true here) ----
  if (Bc > 0) {
    // histogram on top-9 random bits (key bits 54..46)
    for (int i = tid; i < F; i += BLOCK)
      atomicAdd(&s_hist[(int)(s_key[i] >> 46) & 511], 1);
    __syncthreads();
    // exclusive scan of 512 buckets (8 waves of 64 + cross-wave offsets)
    int hv = s_hist[wv * 64 + lane];
    int hx = hv;
    for (int off = 1; off < 64; off <<= 1) { int n = __shfl_up(hx, off); if (lane >= off) hx += n; }
    if (lane == 63) s_wtot[wv] = hx;
    __syncthreads();
    int woff = 0;
    for (int w = 0; w < wv; ++w) woff += s_wtot[w];
    s_hist[wv * 64 + lane] = woff + hx - hv;   // in-place: now cum[bucket]
    __syncthreads();
    // candidates: keys in buckets with cum < 64
    for (int i = tid; i < F; i += BLOCK) {
      uint64_t k = s_key[i];
      if (s_hist[(int)(k >> 46) & 511] < FGPER) {
        int pos = atomicAdd(&s_candN, 1);
        if (pos < CANDMAX) s_cand[pos] = k;
      }
    }
    __syncthreads();
    int candN = s_candN;
    if (candN <= CANDMAX) {
      // exact global rank per candidate (4 threads per candidate)
      int ci = tid >> 2, ch = tid & 3;
      if (ci < candN) {
        uint64_t kc = s_cand[ci];
        int lo = (F * ch) >> 2, hi = (F * (ch + 1)) >> 2;
        int cnt = 0;
        for (int j = lo; j < hi; ++j) cnt += (s_key[j] < kc) ? 1 : 0;
        atomicAdd(&s_crank[ci], cnt);
      }
      __syncthreads();
      if (tid < candN && tid < CANDMAX) {
        int r = s_crank[tid];
        if (r < FGPER) s_ford[r] = (unsigned short)(s_cand[tid] & 0xFFFFull);
      }
    } else {
      // paranoia fallback: full stable rank
      for (int i = tid; i < F; i += BLOCK) {
        uint64_t ki = s_key[i];
        int r = 0;
        for (int j = 0; j < F; ++j) r += (s_key[j] < ki) ? 1 : 0;
        s_ford[r] = (unsigned short)(ki & 0xFFFFull);
      }
    }
  } else {
    // Bc==0 (never for this data): need full fg order
    for (int i = tid; i < F; i += BLOCK) {
      uint64_t ki = s_key[i];
      int r = 0;
      for (int j = 0; j < F; ++j) r += (s_key[j] < ki) ? 1 : 0;
      s_ford[r] = (unsigned short)(ki & 0xFFFFull);
    }
  }
  __syncthreads();

  // ---- sampling + bbox transform + output ----
  if (tid < ROUT) {
    const int j = tid;
    float rfg = u01f(tf_bits32(kr0, kr1, (uint32_t)j));   // uniform(kr,(R,))
    float rbg = u01f(tf_bits32(kb0, kb1, (uint32_t)j));   // uniform(kb,(R,))

    int fg_this = (Bc > 0) ? (F < FGPER ? F : FGPER) : ((F > 0) ? ROUT : 0);
    int keep; float lab;
    if (j < fg_this) {
      int p;
      if (j < F) { p = j; }
      else {
        p = (int)(__fmul_rn(rfg, (float)(F < 1 ? 1 : F)));  // trunc like astype(int32)
        if (p > NT - 1) p = NT - 1;
        if (p < 0) p = 0;
      }
      keep = (p < F) ? (int)s_ford[p] : nth_non(cp, p - F, 0);
      lab = s_glb[cp[keep] & 0xFF];
    } else {
      int q = (int)(__fmul_rn(rbg, (float)(Bc < 1 ? 1 : Bc)));
      if (q > NT - 1) q = NT - 1;
      if (q < 0) q = 0;
      if (Bc > 0) keep = (q < Bc) ? (int)s_bidx[q] : nth_non(cp, q - Bc, 1);
      else        keep = q;   // no bg: argsort of all-2.0 is identity
      lab = 0.0f;
    }

    float ex1, ey1, ex2, ey2;
    if (keep < NROI) {
      const float* p = all_rois + ((size_t)b * NROI + keep) * 5;
      ex1 = p[1]; ey1 = p[2]; ex2 = p[3]; ey2 = p[4];
    } else {
      int k = keep - NROI;
      ex1 = s_gx1[k]; ey1 = s_gy1[k]; ex2 = s_gx2[k]; ey2 = s_gy2[k];
    }
    int ga = cp[keep] & 0xFF;
    float gx1 = s_gx1[ga], gy1 = s_gy1[ga], gx2 = s_gx2[ga], gy2 = s_gy2[ga];

    float ew = ex2 - ex1 + 1.0f, eh = ey2 - ey1 + 1.0f;
    float ecx = ex1 + 0.5f * ew, ecy = ey1 + 0.5f * eh;
    float gw = gx2 - gx1 + 1.0f, gh = gy2 - gy1 + 1.0f;
    float gcx = gx1 + 0.5f * gw, gcy = gy1 + 0.5f * gh;
    float tt[4];
    tt[0] = (gcx - ecx) / ew;
    tt[1] = (gcy - ecy) / eh;
    tt[2] = logf(gw / ew);
    tt[3] = logf(gh / eh);
    bool isfg = (lab > 0.0f);

    size_t roff = (size_t)b * ROUT + j;
    float* po = out + roff * 5;
    po[0] = (float)b; po[1] = ex1; po[2] = ey1; po[3] = ex2; po[4] = ey2;
    out[(size_t)NB * ROUT * 5 + roff] = lab;
    float* pt = out + (size_t)NB * ROUT * 6 + roff * 4;
    float* pi = out + (size_t)NB * ROUT * 10 + roff * 4;
    float* pq = out + (size_t)NB * ROUT * 14 + roff * 4;
    for (int c = 0; c < 4; ++c) {
      float tn = (tt[c] - bmeans[c]) / bstds[c];
      float vi = isfg ? binw[c] : 0.0f;
      pt[c] = isfg ? tn : 0.0f;
      pi[c] = vi;
      pq[c] = (vi > 0.0f) ? 1.0f : 0.0f;
    }
  }
}

extern "C" void kernel_launch(void* const* d_in, const int* in_sizes, int n_in,
                              void* d_out, int out_size, void* d_ws, size_t ws_size,
                              hipStream_t stream) {
  const float* all_rois = (const float*)d_in[0];
  const float* gt_boxes = (const float*)d_in[1];
  // d_in[2] = num_boxes (unused, as in the reference)
  const float* bmeans = (const float*)d_in[3];
  const float* bstds  = (const float*)d_in[4];
  const float* binw   = (const float*)d_in[5];
  float* out = (float*)d_out;

  unsigned short* cls_ws = (unsigned short*)d_ws;   // NB*NT u16

  // DIAGNOSTIC: iou launched twice (idempotent — second writes identical values).
  // dur_us delta vs R10 (113.4) measures one iou instance + dispatch overhead.
  iou_kernel<<<dim3(NCHA, NB), dim3(BLOCKA), 0, stream>>>(all_rois, gt_boxes, cls_ws);
  iou_kernel<<<dim3(NCHA, NB), dim3(BLOCKA), 0, stream>>>(all_rois, gt_boxes, cls_ws);
  sample_kernel<<<dim3(NB), dim3(BLOCK), 0, stream>>>(all_rois, gt_boxes, cls_ws,
                                                      bmeans, bstds, binw, out);
}

// Round 12
// 111.740 us; speedup vs baseline: 1.2374x; 1.2374x over previous
//
#include <hip/hip_runtime.h>
#include <stdint.h>

#define NB    64      // batch
#define NROI  6000    // proposals per image
#define KGT   100     // gt slots per image
#define NT    6100    // NROI + KGT
#define ROUT  256     // sampled rois per image
#define FGPER 64

#define BLOCKA 256                      // iou block
#define ROIS_PER_BLOCK (BLOCKA * 2)     // 2 rois per thread
#define NCHA ((NT + ROIS_PER_BLOCK - 1) / ROIS_PER_BLOCK)   // 12 chunks
#define CHUNK 8                         // GTs staged into registers per chunk

#define BLOCK 512
#define NWAVE (BLOCK / 64)
#define CANDMAX 128

// class encoding in ws u16: (cls << 8) | gt_assign ; cls: 2=fg, 1=bg, 0=neg(-1 row)
#define CLS_FG 2
#define CLS_BG 1
#define CLS_NEG 0

// d_ws layout (bytes):
//   [0)        u16 cls_ws[NB][NT]              780800
//   [780800)   int2 counts[NB][NCHA]           6144
//   [786944)   u64 fgk[NB][NCHA][512]          3145728
//   [3932672)  u16 bgi[NB][NCHA][512]          786432

__device__ __forceinline__ uint32_t rotl32(uint32_t v, int s) { return (v << s) | (v >> (32 - s)); }

// Exact replica of JAX threefry2x32 (20 rounds)
#define TFR(r) { x0 += x1; x1 = rotl32(x1, r); x1 ^= x0; }
__device__ __forceinline__ void tf2x32(uint32_t k0, uint32_t k1, uint32_t& x0, uint32_t& x1) {
  uint32_t k2 = k0 ^ k1 ^ 0x1BD11BDAu;
  x0 += k0; x1 += k1;
  TFR(13) TFR(15) TFR(26) TFR(6)
  x0 += k1; x1 += k2 + 1u;
  TFR(17) TFR(29) TFR(16) TFR(24)
  x0 += k2; x1 += k0 + 2u;
  TFR(13) TFR(15) TFR(26) TFR(6)
  x0 += k0; x1 += k1 + 3u;
  TFR(17) TFR(29) TFR(16) TFR(24)
  x0 += k1; x1 += k2 + 4u;
  TFR(13) TFR(15) TFR(26) TFR(6)
  x0 += k2; x1 += k0 + 5u;
}

// jax_threefry_partitionable=True (default since JAX 0.4.36):
// bits for flat index i = fold(TF(key, (0, i))) = out0 ^ out1
__device__ __forceinline__ uint32_t tf_bits32(uint32_t k0, uint32_t k1, uint32_t idx) {
  uint32_t x0 = 0u, x1 = idx;
  tf2x32(k0, k1, x0, x1);
  return x0 ^ x1;
}

// JAX uniform [0,1): bitcast(bits>>9 | 0x3F800000) - 1.0
__device__ __forceinline__ float u01f(uint32_t bits) {
  return __uint_as_float((bits >> 9) | 0x3F800000u) - 1.0f;
}

// Correctly-rounded f32 divide (canonical div_scale/rcp/NR/div_fmas/div_fixup).
// Bit-identical to IEEE fdiv on this kernel's operand domain (no denormals).
__device__ __forceinline__ float crdiv(float num, float den) {
  bool f0, f1;
  float ds = __builtin_amdgcn_div_scalef(num, den, false, &f0);
  float ns = __builtin_amdgcn_div_scalef(num, den, true,  &f1);
  float r  = __builtin_amdgcn_rcpf(ds);
  float e0 = __builtin_fmaf(-ds, r, 1.0f);
  float r1 = __builtin_fmaf(e0, r, r);
  float m  = ns * r1;
  float e1 = __builtin_fmaf(-ds, m, ns);
  float r2 = __builtin_fmaf(e1, r1, m);
  float e2 = __builtin_fmaf(-ds, r2, ns);
  float fm = __builtin_amdgcn_div_fmasf(e2, r1, r2, f1);
  return __builtin_amdgcn_div_fixupf(fm, den, num);
}

// ============ kernel A: IoU max/argmax + per-chunk compaction ============
// grid (NCHA, NB) x BLOCKA, 2 rois/thread. Writes cls_ws AND per-chunk
// compacted fg keys (with threefry bits) / bg indices / counts.
__global__ __launch_bounds__(BLOCKA) void iou_kernel(
    const float* __restrict__ all_rois,   // [NB, NROI, 5]
    const float* __restrict__ gt_boxes,   // [NB, KGT, 5]
    unsigned short* __restrict__ cls_ws,  // [NB, NT]
    int2* __restrict__ counts,            // [NB, NCHA]
    uint64_t* __restrict__ fgk,           // [NB, NCHA, 512]
    unsigned short* __restrict__ bgi)     // [NB, NCHA, 512]
{
#pragma clang fp contract(off)
  __shared__ float s_gx1[KGT], s_gy1[KGT], s_gx2[KGT], s_gy2[KGT];   // original order
  __shared__ float4 s_cg[KGT + CHUNK];    // compacted valid (x1,y1,x2,y2)
  __shared__ float s_car[KGT + CHUNK];    // compacted area
  __shared__ short s_ck[KGT];             // compacted -> original k
  __shared__ unsigned long long s_zm[2];
  __shared__ int s_V, s_minz;
  __shared__ int s_segf[8], s_segb[8];    // per-segment fg/bg counts -> offsets

  const int b = blockIdx.y;
  const int tid = threadIdx.x;
  const int lane = tid & 63, wv = tid >> 6;

  bool nz = false;
  float gx1v = 0, gy1v = 0, gx2v = 0, gy2v = 0, garv = 0;
  if (tid < KGT) {
    const float* g = gt_boxes + ((size_t)b * KGT + tid) * 5;
    gx1v = g[0]; gy1v = g[1]; gx2v = g[2]; gy2v = g[3];
    s_gx1[tid] = gx1v; s_gy1[tid] = gy1v; s_gx2[tid] = gx2v; s_gy2[tid] = gy2v;
    float wg = __fadd_rn(__fadd_rn(gx2v, -gx1v), 1.0f);
    float hg = __fadd_rn(__fadd_rn(gy2v, -gy1v), 1.0f);
    garv = __fmul_rn(wg, hg);
    nz = !(wg == 1.0f && hg == 1.0f);
  }
  if (wv < 2) {
    unsigned long long bm = __ballot(nz);
    if (lane == 0) s_zm[wv] = bm;
  }
  __syncthreads();
  if (tid == 0) {
    unsigned long long z0 = s_zm[0], z1 = s_zm[1];
    unsigned long long g0 = ~z0;
    unsigned long long g1 = (~z1) & ((1ull << (KGT - 64)) - 1ull);
    int mz = -1;
    if (g0) mz = __ffsll((long long)g0) - 1;
    else if (g1) mz = 64 + __ffsll((long long)g1) - 1;
    s_minz = mz;
    s_V = __popcll(z0) + __popcll(z1);
  }
  if (tid < KGT && nz) {
    unsigned long long lm = (1ull << lane) - 1ull;
    int pos = (wv == 0) ? __popcll(s_zm[0] & lm)
                        : __popcll(s_zm[0]) + __popcll(s_zm[1] & lm);
    s_cg[pos] = make_float4(gx1v, gy1v, gx2v, gy2v);
    s_car[pos] = garv; s_ck[pos] = (short)tid;
  }
  __syncthreads();
  const int V = s_V, minz = s_minz;

  if (tid < CHUNK) { s_cg[V + tid] = make_float4(0.f, 0.f, 0.f, 0.f); s_car[V + tid] = 1.0f; }
  __syncthreads();

  const int base = blockIdx.x * ROIS_PER_BLOCK;
  const int t0 = base + tid, t1 = base + BLOCKA + tid;

  // load two rois (guarded)
  float x1a, y1a, x2a, y2a, x1b, y1b, x2b, y2b;
  {
    int ta = (t0 < NT) ? t0 : 0;
    if (ta < NROI) {
      const float* p = all_rois + ((size_t)b * NROI + ta) * 5;
      x1a = p[1]; y1a = p[2]; x2a = p[3]; y2a = p[4];
    } else {
      int k = ta - NROI;
      x1a = s_gx1[k]; y1a = s_gy1[k]; x2a = s_gx2[k]; y2a = s_gy2[k];
    }
    int tb = (t1 < NT) ? t1 : 0;
    if (tb < NROI) {
      const float* p = all_rois + ((size_t)b * NROI + tb) * 5;
      x1b = p[1]; y1b = p[2]; x2b = p[3]; y2b = p[4];
    } else {
      int k = tb - NROI;
      x1b = s_gx1[k]; y1b = s_gy1[k]; x2b = s_gx2[k]; y2b = s_gy2[k];
    }
  }
  float wra = __fadd_rn(__fadd_rn(x2a, -x1a), 1.0f);
  float hra = __fadd_rn(__fadd_rn(y2a, -y1a), 1.0f);
  float ara = __fmul_rn(wra, hra);
  bool rza = (wra == 1.0f && hra == 1.0f);
  float wrb = __fadd_rn(__fadd_rn(x2b, -x1b), 1.0f);
  float hrb = __fadd_rn(__fadd_rn(y2b, -y1b), 1.0f);
  float arb = __fmul_rn(wrb, hrb);
  bool rzb = (wrb == 1.0f && hrb == 1.0f);

  float besta = -2.0f, bestb = -2.0f;
  int bva = -1, bvb = -1;

  for (int c0 = 0; c0 < V; c0 += CHUNK) {
    float4 g[CHUNK];
    float ca[CHUNK];
#pragma unroll
    for (int i = 0; i < CHUNK; ++i) { g[i] = s_cg[c0 + i]; ca[i] = s_car[c0 + i]; }
#pragma unroll
    for (int i = 0; i < CHUNK; ++i) {
      const int vv = c0 + i;
      const float cx1 = g[i].x, cy1 = g[i].y, cx2 = g[i].z, cy2 = g[i].w, car = ca[i];
      {
        float iw = fmaxf(__fadd_rn(__fadd_rn(fminf(x2a, cx2), -fmaxf(x1a, cx1)), 1.0f), 0.0f);
        float ih = fmaxf(__fadd_rn(__fadd_rn(fminf(y2a, cy2), -fmaxf(y1a, cy1)), 1.0f), 0.0f);
        float inter = __fmul_rn(iw, ih);
        float ov = crdiv(inter, __fadd_rn(__fadd_rn(ara, car), -inter));
        if (vv < V && ov > besta) { besta = ov; bva = vv; }
      }
      {
        float iw = fmaxf(__fadd_rn(__fadd_rn(fminf(x2b, cx2), -fmaxf(x1b, cx1)), 1.0f), 0.0f);
        float ih = fmaxf(__fadd_rn(__fadd_rn(fminf(y2b, cy2), -fmaxf(y1b, cy1)), 1.0f), 0.0f);
        float inter = __fmul_rn(iw, ih);
        float ov = crdiv(inter, __fadd_rn(__fadd_rn(arb, car), -inter));
        if (vv < V && ov > bestb) { bestb = ov; bvb = vv; }
      }
    }
  }

  int bka = (bva >= 0) ? (int)s_ck[bva] : 0;
  int bkb = (bvb >= 0) ? (int)s_ck[bvb] : 0;
  if (rza) { besta = -1.0f; bka = 0; }
  else {
    if (besta < 0.0f) { besta = 0.0f; bka = (minz >= 0 ? minz : 0); }
    else if (besta == 0.0f && minz >= 0 && minz < bka) bka = minz;
  }
  if (rzb) { bestb = -1.0f; bkb = 0; }
  else {
    if (bestb < 0.0f) { bestb = 0.0f; bkb = (minz >= 0 ? minz : 0); }
    else if (bestb == 0.0f && minz >= 0 && minz < bkb) bkb = minz;
  }
  int clsa = (besta >= 0.5f) ? CLS_FG : ((besta >= 0.0f) ? CLS_BG : CLS_NEG);
  int clsb = (bestb >= 0.5f) ? CLS_FG : ((bestb >= 0.0f) ? CLS_BG : CLS_NEG);
  if (t0 < NT) cls_ws[(size_t)b * NT + t0] = (unsigned short)((clsa << 8) | bka);
  if (t1 < NT) cls_ws[(size_t)b * NT + t1] = (unsigned short)((clsb << 8) | bkb);

  // ---- per-chunk compaction: fg keys (threefry bits) + bg indices + counts ----
  // per-image kf key (uniform across block): kf = TF(TF((0,42),(0,b)), (0,0))
  uint32_t kk0 = 0u, kk1 = (uint32_t)b;
  tf2x32(0u, 42u, kk0, kk1);
  uint32_t kf0 = 0u, kf1 = 0u; tf2x32(kk0, kk1, kf0, kf1);

  bool fga = (t0 < NT) && (clsa == CLS_FG);
  bool bga = (t0 < NT) && (clsa == CLS_BG);
  bool fgb = (t1 < NT) && (clsb == CLS_FG);
  bool bgb = (t1 < NT) && (clsb == CLS_BG);
  unsigned long long mfa = __ballot(fga), mba = __ballot(bga);
  unsigned long long mfb = __ballot(fgb), mbb = __ballot(bgb);
  if (lane == 0) {
    s_segf[wv] = __popcll(mfa);     s_segb[wv] = __popcll(mba);
    s_segf[4 + wv] = __popcll(mfb); s_segb[4 + wv] = __popcll(mbb);
  }
  __syncthreads();
  if (tid == 0) {
    int af = 0, ab = 0;
    for (int s2 = 0; s2 < 8; ++s2) {
      int cf = s_segf[s2], cb = s_segb[s2];
      s_segf[s2] = af; s_segb[s2] = ab;
      af += cf; ab += cb;
    }
    counts[(size_t)b * NCHA + blockIdx.x] = make_int2(af, ab);
  }
  __syncthreads();
  unsigned long long lm = (1ull << lane) - 1ull;
  size_t cbase = ((size_t)b * NCHA + blockIdx.x) * 512;
  if (fga) {
    uint32_t ub = tf_bits32(kf0, kf1, (uint32_t)t0);
    fgk[cbase + s_segf[wv] + __popcll(mfa & lm)] = (((uint64_t)(ub >> 9)) << 32) | (uint32_t)t0;
  }
  if (bga) bgi[cbase + s_segb[wv] + __popcll(mba & lm)] = (unsigned short)t0;
  if (fgb) {
    uint32_t ub = tf_bits32(kf0, kf1, (uint32_t)t1);
    fgk[cbase + s_segf[4 + wv] + __popcll(mfb & lm)] = (((uint64_t)(ub >> 9)) << 32) | (uint32_t)t1;
  }
  if (bgb) bgi[cbase + s_segb[4 + wv] + __popcll(mbb & lm)] = (unsigned short)t1;
}

// p-th (0-based) index t whose mask is FALSE, ascending (argsort 2.0-pad region).
// Dead on this data (kept for exact semantics in degenerate cases).
__device__ int nth_non(const unsigned short* cp, int n, int mode) {
  int c = 0;
  for (int t = 0; t < NT; ++t) {
    int cls = cp[t] >> 8;
    bool member = (mode == 0) ? (cls == CLS_FG) : (cls == CLS_BG);
    if (!member) { if (c == n) return t; ++c; }
  }
  return NT - 1;
}

// ============ kernel B: gather compacted lists + select + sampling ============
__global__ __launch_bounds__(BLOCK) void sample_kernel(
    const float* __restrict__ all_rois,
    const float* __restrict__ gt_boxes,
    const unsigned short* __restrict__ cls_ws,
    const int2* __restrict__ counts,
    const uint64_t* __restrict__ fgk,
    const unsigned short* __restrict__ bgi,
    const float* __restrict__ bmeans,
    const float* __restrict__ bstds,
    const float* __restrict__ binw,
    float* __restrict__ out)
{
#pragma clang fp contract(off)
  __shared__ float s_gx1[KGT], s_gy1[KGT], s_gx2[KGT], s_gy2[KGT], s_glb[KGT];
  __shared__ uint64_t s_key[NT];
  __shared__ unsigned short s_bidx[NT];
  __shared__ unsigned short s_ford[NT];
  __shared__ int s_foff[NCHA + 1], s_boff[NCHA + 1];
  __shared__ int s_hist[512];
  __shared__ int s_wtot[NWAVE];
  __shared__ uint64_t s_cand[CANDMAX];
  __shared__ int s_crank[CANDMAX];
  __shared__ int s_candN;

  const int b = blockIdx.x;
  const int tid = threadIdx.x;
  const int lane = tid & 63, wv = tid >> 6;
  const unsigned short* cp = cls_ws + (size_t)b * NT;

  if (tid < KGT) {
    const float* g = gt_boxes + ((size_t)b * KGT + tid) * 5;
    s_gx1[tid] = g[0]; s_gy1[tid] = g[1]; s_gx2[tid] = g[2]; s_gy2[tid] = g[3]; s_glb[tid] = g[4];
  }
  s_hist[tid] = 0;                      // BLOCK == 512 exactly
  if (tid < CANDMAX) s_crank[tid] = 0;
  if (tid == 0) s_candN = 0;

  // chunk-count prefix sums
  if (tid == 0) {
    int af = 0, ab = 0;
    for (int c = 0; c < NCHA; ++c) {
      int2 cc = counts[(size_t)b * NCHA + c];
      s_foff[c] = af; s_boff[c] = ab;
      af += cc.x; ab += cc.y;
    }
    s_foff[NCHA] = af; s_boff[NCHA] = ab;
  }

  // per-image keys kb, kr (kf now consumed in iou_kernel)
  uint32_t kk0 = 0u, kk1 = (uint32_t)b;
  tf2x32(0u, 42u, kk0, kk1);
  uint32_t kb0 = 0u, kb1 = 1u; tf2x32(kk0, kk1, kb0, kb1);
  uint32_t kr0 = 0u, kr1 = 2u; tf2x32(kk0, kk1, kr0, kr1);
  __syncthreads();
  const int F = s_foff[NCHA], Bc = s_boff[NCHA];

  // gather per-chunk compacted lists into contiguous LDS (waves independent)
  for (int c = wv; c < NCHA; c += NWAVE) {
    size_t cbase = ((size_t)b * NCHA + c) * 512;
    int fo = s_foff[c], nf = s_foff[c + 1] - fo;
    int bo = s_boff[c], nb = s_boff[c + 1] - bo;
    for (int i = lane; i < nf; i += 64) s_key[fo + i] = fgk[cbase + i];
    for (int i = lane; i < nb; i += 64) s_bidx[bo + i] = bgi[cbase + i];
  }
  __syncthreads();

  // ---- rank-select: only ranks < 64 are read when Bc>0 (always true here) ----
  if (Bc > 0) {
    for (int i = tid; i < F; i += BLOCK)
      atomicAdd(&s_hist[(int)(s_key[i] >> 46) & 511], 1);
    __syncthreads();
    int hv = s_hist[wv * 64 + lane];
    int hx = hv;
    for (int off = 1; off < 64; off <<= 1) { int n = __shfl_up(hx, off); if (lane >= off) hx += n; }
    if (lane == 63) s_wtot[wv] = hx;
    __syncthreads();
    int woff = 0;
    for (int w = 0; w < wv; ++w) woff += s_wtot[w];
    s_hist[wv * 64 + lane] = woff + hx - hv;   // now cum[bucket]
    __syncthreads();
    for (int i = tid; i < F; i += BLOCK) {
      uint64_t k = s_key[i];
      if (s_hist[(int)(k >> 46) & 511] < FGPER) {
        int pos = atomicAdd(&s_candN, 1);
        if (pos < CANDMAX) s_cand[pos] = k;
      }
    }
    __syncthreads();
    int candN = s_candN;
    if (candN <= CANDMAX) {
      int ci = tid >> 2, ch = tid & 3;
      if (ci < candN) {
        uint64_t kc = s_cand[ci];
        int lo = (F * ch) >> 2, hi = (F * (ch + 1)) >> 2;
        int cnt = 0;
        for (int j = lo; j < hi; ++j) cnt += (s_key[j] < kc) ? 1 : 0;
        atomicAdd(&s_crank[ci], cnt);
      }
      __syncthreads();
      if (tid < candN && tid < CANDMAX) {
        int r = s_crank[tid];
        if (r < FGPER) s_ford[r] = (unsigned short)(s_cand[tid] & 0xFFFFull);
      }
    } else {
      for (int i = tid; i < F; i += BLOCK) {
        uint64_t ki = s_key[i];
        int r = 0;
        for (int j = 0; j < F; ++j) r += (s_key[j] < ki) ? 1 : 0;
        s_ford[r] = (unsigned short)(ki & 0xFFFFull);
      }
    }
  } else {
    for (int i = tid; i < F; i += BLOCK) {
      uint64_t ki = s_key[i];
      int r = 0;
      for (int j = 0; j < F; ++j) r += (s_key[j] < ki) ? 1 : 0;
      s_ford[r] = (unsigned short)(ki & 0xFFFFull);
    }
  }
  __syncthreads();

  // ---- sampling + bbox transform + output ----
  if (tid < ROUT) {
    const int j = tid;
    float rfg = u01f(tf_bits32(kr0, kr1, (uint32_t)j));   // uniform(kr,(R,))
    float rbg = u01f(tf_bits32(kb0, kb1, (uint32_t)j));   // uniform(kb,(R,))

    int fg_this = (Bc > 0) ? (F < FGPER ? F : FGPER) : ((F > 0) ? ROUT : 0);
    int keep; float lab;
    if (j < fg_this) {
      int p;
      if (j < F) { p = j; }
      else {
        p = (int)(__fmul_rn(rfg, (float)(F < 1 ? 1 : F)));  // trunc like astype(int32)
        if (p > NT - 1) p = NT - 1;
        if (p < 0) p = 0;
      }
      keep = (p < F) ? (int)s_ford[p] : nth_non(cp, p - F, 0);
      lab = s_glb[cp[keep] & 0xFF];
    } else {
      int q = (int)(__fmul_rn(rbg, (float)(Bc < 1 ? 1 : Bc)));
      if (q > NT - 1) q = NT - 1;
      if (q < 0) q = 0;
      if (Bc > 0) keep = (q < Bc) ? (int)s_bidx[q] : nth_non(cp, q - Bc, 1);
      else        keep = q;   // no bg: argsort of all-2.0 is identity
      lab = 0.0f;
    }

    float ex1, ey1, ex2, ey2;
    if (keep < NROI) {
      const float* p = all_rois + ((size_t)b * NROI + keep) * 5;
      ex1 = p[1]; ey1 = p[2]; ex2 = p[3]; ey2 = p[4];
    } else {
      int k = keep - NROI;
      ex1 = s_gx1[k]; ey1 = s_gy1[k]; ex2 = s_gx2[k]; ey2 = s_gy2[k];
    }
    int ga = cp[keep] & 0xFF;
    float gx1 = s_gx1[ga], gy1 = s_gy1[ga], gx2 = s_gx2[ga], gy2 = s_gy2[ga];

    float ew = ex2 - ex1 + 1.0f, eh = ey2 - ey1 + 1.0f;
    float ecx = ex1 + 0.5f * ew, ecy = ey1 + 0.5f * eh;
    float gw = gx2 - gx1 + 1.0f, gh = gy2 - gy1 + 1.0f;
    float gcx = gx1 + 0.5f * gw, gcy = gy1 + 0.5f * gh;
    float tt[4];
    tt[0] = (gcx - ecx) / ew;
    tt[1] = (gcy - ecy) / eh;
    tt[2] = logf(gw / ew);
    tt[3] = logf(gh / eh);
    bool isfg = (lab > 0.0f);

    size_t roff = (size_t)b * ROUT + j;
    float* po = out + roff * 5;
    po[0] = (float)b; po[1] = ex1; po[2] = ey1; po[3] = ex2; po[4] = ey2;
    out[(size_t)NB * ROUT * 5 + roff] = lab;
    float* pt = out + (size_t)NB * ROUT * 6 + roff * 4;
    float* pi = out + (size_t)NB * ROUT * 10 + roff * 4;
    float* pq = out + (size_t)NB * ROUT * 14 + roff * 4;
    for (int c = 0; c < 4; ++c) {
      float tn = (tt[c] - bmeans[c]) / bstds[c];
      float vi = isfg ? binw[c] : 0.0f;
      pt[c] = isfg ? tn : 0.0f;
      pi[c] = vi;
      pq[c] = (vi > 0.0f) ? 1.0f : 0.0f;
    }
  }
}

extern "C" void kernel_launch(void* const* d_in, const int* in_sizes, int n_in,
                              void* d_out, int out_size, void* d_ws, size_t ws_size,
                              hipStream_t stream) {
  const float* all_rois = (const float*)d_in[0];
  const float* gt_boxes = (const float*)d_in[1];
  // d_in[2] = num_boxes (unused, as in the reference)
  const float* bmeans = (const float*)d_in[3];
  const float* bstds  = (const float*)d_in[4];
  const float* binw   = (const float*)d_in[5];
  float* out = (float*)d_out;

  char* ws = (char*)d_ws;
  unsigned short* cls_ws = (unsigned short*)ws;              // [NB][NT] u16, 780800 B
  int2* counts = (int2*)(ws + 780800);                       // [NB][NCHA], 6144 B
  uint64_t* fgk = (uint64_t*)(ws + 786944);                  // [NB][NCHA][512] u64
  unsigned short* bgi = (unsigned short*)(ws + 3932672);     // [NB][NCHA][512] u16

  iou_kernel<<<dim3(NCHA, NB), dim3(BLOCKA), 0, stream>>>(all_rois, gt_boxes, cls_ws,
                                                          counts, fgk, bgi);
  sample_kernel<<<dim3(NB), dim3(BLOCK), 0, stream>>>(all_rois, gt_boxes, cls_ws,
                                                      counts, fgk, bgi,
                                                      bmeans, bstds, binw, out);
}